// Round 8
// baseline (2933.116 us; speedup 1.0000x reference)
//
#include <hip/hip_runtime.h>

#define B_SZ 512
#define T_ENC 140
#define E_DIM 256
#define H_DIM 512
#define O_DIM 64
#define PRED 140
#define T_TOT 280
#define NBLK 256
#define HBUF 262144   // shorts per h16 buffer (8 islands * 32768)

typedef short bf16x8 __attribute__((ext_vector_type(8)));
typedef float f32x4 __attribute__((ext_vector_type(4)));
typedef unsigned u32x4 __attribute__((ext_vector_type(4)));

static __device__ __forceinline__ unsigned short f2b(float x){
  union { float f; unsigned u; } v; v.f = x;
  unsigned r = v.u + 0x7fffu + ((v.u >> 16) & 1u);
  return (unsigned short)(r >> 16);
}
static __device__ __forceinline__ float sigmoidf_(float x){
  return 1.0f / (1.0f + __expf(-x));
}
static __device__ __forceinline__ float tanhf_(float x){
  float e2 = __expf(-2.0f * fabsf(x));
  float t = (1.0f - e2) / (1.0f + e2);
  return x < 0.0f ? -t : t;
}

// transports: FAST = same-XCD local L2 (plain stores; sc0=GLC loads force L1 miss -> read local L2)
//             SLOW = device-coherent via MALL (sc0 sc1)
template<bool FAST>
static __device__ __forceinline__ bf16x8 ldx4a(const unsigned short* p){
  f32x4 r;
  if constexpr (FAST) asm volatile("global_load_dwordx4 %0, %1, off sc0" : "=v"(r) : "v"(p));
  else                asm volatile("global_load_dwordx4 %0, %1, off sc0 sc1" : "=v"(r) : "v"(p));
  union { f32x4 f; bf16x8 b; } u; u.f = r; return u.b;
}
template<bool FAST>
static __device__ __forceinline__ void st16(unsigned short* p, unsigned v){
  if constexpr (FAST) asm volatile("global_store_short %0, %1, off" :: "v"(p), "v"(v) : "memory");
  else                asm volatile("global_store_short %0, %1, off sc0 sc1" :: "v"(p), "v"(v) : "memory");
}
static __device__ __forceinline__ void wait_vm0(){
  asm volatile("s_waitcnt vmcnt(0)" ::: "memory");
  __builtin_amdgcn_sched_barrier(0);
}
static __device__ __forceinline__ unsigned ld_mall(const unsigned* p){
  unsigned r;
  asm volatile("global_load_dword %0, %1, off sc0 sc1\n\ts_waitcnt vmcnt(0)" : "=v"(r) : "v"(p) : "memory");
  return r;
}
static __device__ __forceinline__ void st_mall(unsigned* p, unsigned v){
  asm volatile("global_store_dword %0, %1, off sc0 sc1\n\ts_waitcnt vmcnt(0)" :: "v"(p), "v"(v) : "memory");
}

__global__ void k_cast(const float* __restrict__ src, unsigned short* __restrict__ dst, int n){
  int i = blockIdx.x * 256 + threadIdx.x;
  if (i < n) dst[i] = f2b(src[i]);
}

__global__ void k_transpose_cast(const float* __restrict__ src, unsigned short* __restrict__ dst){
  int i = blockIdx.x * 256 + threadIdx.x;   // over H*E = 131072
  int j = i >> 8;
  int k = i & 255;
  dst[i] = f2b(src[k * H_DIM + j]);
}

// h16 buffer 1 (parity s=-1) in PACKED layout [rg][sl][row][16]
__global__ void k_init_h(const float* __restrict__ eh, unsigned short* __restrict__ h16){
  int i = blockIdx.x * 256 + threadIdx.x;   // B*H
  int b = i >> 9, col = i & 511;
  h16[HBUF + (((size_t)(b >> 6) * 32 + (col >> 4)) * 64 + (b & 63)) * 16 + (col & 15)] = f2b(eh[i]);
}

__global__ void k_x0(const float* __restrict__ enc, unsigned short* __restrict__ x016){
  int i = blockIdx.x * 256 + threadIdx.x;   // B*E
  int b = i >> 8; int k = i & 255;
  x016[i] = f2b(enc[((size_t)b * T_ENC + (T_ENC - 1)) * E_DIM + k]);
}

__global__ void k_dup(const unsigned short* __restrict__ e16, unsigned short* __restrict__ e0c){
  int i = blockIdx.x * 256 + threadIdx.x;   // 262144
  e0c[i] = e16[i];
}

// bias_big = [emb_b + emb_W@out_b (512) | b_hh (1536) | reg_b + reg_W@out_b (64)]
__global__ void k_bias(const float* __restrict__ embW, const float* __restrict__ emb_b,
                       const float* __restrict__ out_b, const float* __restrict__ b_hh,
                       const float* __restrict__ regW, const float* __restrict__ reg_b,
                       float* __restrict__ bias_big){
  int i = blockIdx.x * 256 + threadIdx.x;
  if (i < 512){
    float s = emb_b[i];
    for (int k = 0; k < 256; k++) s += embW[i * 256 + k] * out_b[k];
    bias_big[i] = s;
  } else if (i < 2048){
    bias_big[i] = b_hh[i - 512];
  } else if (i < 2112){
    int o = i - 2048;
    float s = reg_b[o];
    for (int k = 0; k < 256; k++) s += regW[o * 256 + k] * out_b[k];
    bias_big[i] = s;
  }
}

// Generic C = A @ W^T (+bias). modes: 0 f32; 1 bf16; 2 relu bf16; 3 enc remap; 4 relu bf16 PACKED
__global__ __launch_bounds__(256)
void k_gemm(const void* __restrict__ Aptr, int a_is_f32,
            const unsigned short* __restrict__ W,
            const float* __restrict__ bias,
            void* __restrict__ Cptr, int mode,
            int M, int N, int K, int ldc)
{
  const int lane = threadIdx.x & 63;
  const int wave = threadIdx.x >> 6;
  const int ln = lane & 15;
  const int kq = lane >> 4;
  const int m0 = blockIdx.y * 64 + wave * 16;
  const int n0 = blockIdx.x * 64;

  f32x4 acc[4] = {};
  const int arow = m0 + ln;
  const unsigned short* wp = W + (size_t)(n0 + ln) * K + kq * 8;
  const int nk = K >> 5;

  if (a_is_f32){
    const float* ap = (const float*)Aptr + (size_t)arow * K + kq * 8;
    for (int t = 0; t < nk; ++t){
      f32x4 u0 = *(const f32x4*)(ap);
      f32x4 u1 = *(const f32x4*)(ap + 4);
      bf16x8 af;
      af[0] = (short)f2b(u0[0]); af[1] = (short)f2b(u0[1]);
      af[2] = (short)f2b(u0[2]); af[3] = (short)f2b(u0[3]);
      af[4] = (short)f2b(u1[0]); af[5] = (short)f2b(u1[1]);
      af[6] = (short)f2b(u1[2]); af[7] = (short)f2b(u1[3]);
      #pragma unroll
      for (int j = 0; j < 4; j++){
        bf16x8 wf = *(const bf16x8*)(wp + (size_t)(16 * j) * K);
        acc[j] = __builtin_amdgcn_mfma_f32_16x16x32_bf16(af, wf, acc[j], 0, 0, 0);
      }
      ap += 32; wp += 32;
    }
  } else {
    const unsigned short* ap = (const unsigned short*)Aptr + (size_t)arow * K + kq * 8;
    for (int t = 0; t < nk; ++t){
      bf16x8 af = *(const bf16x8*)ap;
      #pragma unroll
      for (int j = 0; j < 4; j++){
        bf16x8 wf = *(const bf16x8*)(wp + (size_t)(16 * j) * K);
        acc[j] = __builtin_amdgcn_mfma_f32_16x16x32_bf16(af, wf, acc[j], 0, 0, 0);
      }
      ap += 32; wp += 32;
    }
  }

  #pragma unroll
  for (int j = 0; j < 4; j++){
    int col = n0 + 16 * j + ln;
    float bv = bias ? bias[col] : 0.0f;
    #pragma unroll
    for (int r = 0; r < 4; r++){
      int orow = m0 + kq * 4 + r;
      float v = acc[j][r] + bv;
      if (mode == 0){
        ((float*)Cptr)[(size_t)orow * ldc + col] = v;
      } else if (mode == 1){
        ((unsigned short*)Cptr)[(size_t)orow * ldc + col] = f2b(v);
      } else if (mode == 2){
        ((unsigned short*)Cptr)[(size_t)orow * ldc + col] = f2b(v > 0.f ? v : 0.f);
      } else if (mode == 3){
        int bb = orow / T_ENC;
        int tt = orow - bb * T_ENC;
        ((float*)Cptr)[((size_t)bb * T_TOT + tt) * O_DIM + col] = v;
      } else {
        ((unsigned short*)Cptr)[(((size_t)(orow >> 6) * 32 + (col >> 4)) * 64 + (orow & 63)) * 16 + (col & 15)]
          = f2b(v > 0.f ? v : 0.f);
      }
    }
  }
}

// ---------------- persistent GRU: XCD islands, gh/h memory-free, packed tiles, binv-free ----------------

static __device__ void gbar_slow(unsigned* slots, int rg, int sl, unsigned gen, int tid){
  asm volatile("s_waitcnt vmcnt(0)" ::: "memory");
  __syncthreads();
  if (tid < 64){
    unsigned* base = slots + rg * 64;
    if (tid == 0){
      asm volatile("global_store_dword %0, %1, off sc0 sc1" :: "v"(base + sl), "v"(gen) : "memory");
    }
    const unsigned* p = base + (tid & 31);
    for (;;){
      unsigned v;
      asm volatile("global_load_dword %0, %1, off sc0 sc1\n\ts_waitcnt vmcnt(0)" : "=v"(v) : "v"(p) : "memory");
      if (__all((int)(v >= gen))) break;
      __builtin_amdgcn_s_sleep(8);
    }
  }
  __syncthreads();
}

// FAST island barrier: local-L2 flags; sc0 loads force L1 miss (no buffer_inv needed); watchdog -> abort.
static __device__ __forceinline__ bool gbar_fast(unsigned* slots, unsigned* abortf,
                                                 volatile unsigned* s_ab, int rg, int sl,
                                                 unsigned gen, int tid){
  asm volatile("s_waitcnt vmcnt(0)" ::: "memory");
  __syncthreads();
  if (tid < 64){
    unsigned* base = slots + rg * 64;
    if (tid == 0){
      asm volatile("global_store_dword %0, %1, off sc0" :: "v"(base + sl), "v"(gen) : "memory");
    }
    const unsigned* p = base + (tid & 31);
    unsigned it = 0, ab = 0;
    for (;;){
      unsigned v;
      asm volatile("global_load_dword %0, %1, off sc0\n\ts_waitcnt vmcnt(0)" : "=v"(v) : "v"(p) : "memory");
      if (__all((int)(v >= gen))) break;
      if ((++it & 2047u) == 0u){
        unsigned a = ld_mall(abortf + rg);
        if (a != 0u || it >= 16384u){
          if (a == 0u && tid == 0) st_mall(abortf + rg, 1u);
          ab = 1u; break;
        }
      }
    }
    if (tid == 0) *s_ab = ab;
  }
  __syncthreads();
  return *s_ab == 0u;
}

// unified step loop; FAST aborts return false. h in VGPRs; gh via LDS handoff; packed tiles.
template<bool FAST>
static __device__ bool run_loop(int rg, int sl,
    const short* wA_e, const short* wA_y, const short* wB_ih, const short* wB_hh,
    float* ghbuf,
    const float* __restrict__ bias_big, const float* __restrict__ b_ih,
    unsigned short* __restrict__ e16,
    unsigned short* __restrict__ h16,
    float* __restrict__ out,
    const float* __restrict__ ehid,
    unsigned* sB, unsigned* sA, unsigned* abortf, volatile unsigned* s_ab, int tid)
{
  const int wv = tid >> 6, lane = tid & 63, ln = lane & 15, kq = lane >> 4;
  const int jcol = sl * 16 + ln;
  // waves 0-3: gi biases; waves 4-7: gh biases (= bias_big[512..2048) = b_hh)
  const float b0 = (wv < 4) ? b_ih[jcol] : bias_big[512 + jcol];
  const float b1 = (wv < 4) ? b_ih[512 + jcol] : bias_big[1024 + jcol];
  const float b2 = (wv < 4) ? b_ih[1024 + jcol] : bias_big[1536 + jcol];
  const float bvE = bias_big[sl * 16 + ln];
  const float bvY = (sl < 4) ? bias_big[2048 + sl * 16 + ln] : 0.f;

  unsigned short* const eb = e16 + (size_t)rg * 32768;      // island e16 base (packed)
  unsigned short* const hb0 = h16 + (size_t)rg * 32768;     // h16 parity-0 island base
  unsigned short* const hb1 = h16 + HBUF + (size_t)rg * 32768;

  // h state in registers (waves 0-3 only)
  float hreg[4];
  if (wv < 4){
    #pragma unroll
    for (int r = 0; r < 4; ++r)
      hreg[r] = ehid[((size_t)rg * 64 + wv * 16 + kq * 4 + r) * H_DIM + jcol];
  }

  const int apoff = (kq >> 1) * 1024 + (kq & 1) * 8;        // packed-tile lane offset

  for (int s = 0; s < PRED; ++s){
    unsigned short* const hw = (s & 1) ? hb1 : hb0;         // h(s)   written by B
    unsigned short* const hr = (s & 1) ? hb0 : hb1;         // h(s-1) read by gh-GEMM

    // ---- phase B: waves 0-3 gi = e@w_ih ; waves 4-7 gh = h(s-1)@w_hh -> LDS ; gating ----
    {
      const unsigned short* ap = (wv < 4)
        ? (eb + apoff + ((wv       * 16 + ln) * 16))
        : (hr + apoff + (((wv - 4) * 16 + ln) * 16));
      bf16x8 af[16];
      #pragma unroll
      for (int t = 0; t < 16; ++t) af[t] = ldx4a<FAST>(ap + t * 2048);
      wait_vm0();
      f32x4 aR = {}, aZ = {}, aN = {};
      const short* lb = ((wv < 4) ? wB_ih : wB_hh) + (ln * 4 + kq) * 8;
      #pragma unroll
      for (int t = 0; t < 16; ++t){
        aR = __builtin_amdgcn_mfma_f32_16x16x32_bf16(af[t], *(const bf16x8*)(lb + (t * 192      ) * 8), aR, 0, 0, 0);
        aZ = __builtin_amdgcn_mfma_f32_16x16x32_bf16(af[t], *(const bf16x8*)(lb + (t * 192 +  64) * 8), aZ, 0, 0, 0);
        aN = __builtin_amdgcn_mfma_f32_16x16x32_bf16(af[t], *(const bf16x8*)(lb + (t * 192 + 128) * 8), aN, 0, 0, 0);
      }
      if (wv >= 4){
        #pragma unroll
        for (int r = 0; r < 4; ++r){
          int row = (wv - 4) * 16 + kq * 4 + r;
          ghbuf[row * 48 + ln]      = aR[r] + b0;
          ghbuf[row * 48 + 16 + ln] = aZ[r] + b1;
          ghbuf[row * 48 + 32 + ln] = aN[r] + b2;
        }
      }
      __syncthreads();
      if (wv < 4){
        #pragma unroll
        for (int r = 0; r < 4; ++r){
          int row = wv * 16 + kq * 4 + r;
          float gR = ghbuf[row * 48 + ln];
          float gZ = ghbuf[row * 48 + 16 + ln];
          float gN = ghbuf[row * 48 + 32 + ln];
          float rr = sigmoidf_(aR[r] + b0 + gR);
          float z  = sigmoidf_(aZ[r] + b1 + gZ);
          float nn = tanhf_(aN[r] + b2 + rr * gN);
          float hv = (1.f - z) * nn + z * hreg[r];
          hreg[r] = hv;
          st16<FAST>(hw + (size_t)sl * 1024 + row * 16 + ln, (unsigned)f2b(hv));
        }
      }
    }
    if constexpr (FAST){
      if (!gbar_fast(sB, abortf, s_ab, rg, sl, (unsigned)(s + 1), tid)) return false;
    } else {
      gbar_slow(sB, rg, sl, (unsigned)(s + 1), tid);
    }

    // ---- phase A: waves 0-3 e-tile sl ; waves 4-7 y-tile (sl<4) ----
    if (wv < 4 || sl < 4){
      const unsigned short* ap = hw + apoff + (((wv & 3) * 16 + ln) * 16);
      bf16x8 af[16];
      #pragma unroll
      for (int t = 0; t < 16; ++t) af[t] = ldx4a<FAST>(ap + t * 2048);
      wait_vm0();
      const short* wf = ((wv < 4) ? wA_e : wA_y) + (ln * 4 + kq) * 8;
      f32x4 acc = {};
      #pragma unroll
      for (int t = 0; t < 16; ++t)
        acc = __builtin_amdgcn_mfma_f32_16x16x32_bf16(af[t], *(const bf16x8*)(wf + (t * 64) * 8), acc, 0, 0, 0);
      if (wv < 4){
        #pragma unroll
        for (int r = 0; r < 4; ++r){
          int row = wv * 16 + kq * 4 + r;
          float v = acc[r] + bvE;
          st16<FAST>(eb + (size_t)sl * 1024 + row * 16 + ln, (unsigned)f2b(v > 0.f ? v : 0.f));
        }
      } else {
        #pragma unroll
        for (int r = 0; r < 4; ++r){
          size_t b = (size_t)rg * 64 + (wv - 4) * 16 + kq * 4 + r;
          out[(b * T_TOT + T_ENC + s) * O_DIM + sl * 16 + ln] = acc[r] + bvY;   // never re-read
        }
      }
    }
    if (s < PRED - 1){
      if constexpr (FAST){
        if (!gbar_fast(sA, abortf, s_ab, rg, sl, (unsigned)(s + 1), tid)) return false;
      } else {
        gbar_slow(sA, rg, sl, (unsigned)(s + 1), tid);
      }
    }
  }
  return true;
}

static __device__ void fast_epilogue(int rg, int sl,
    const short* wA_e, const short* wA_y, const short* wB_ih, const short* wB_hh,
    float* ghbuf,
    const float* bias_big, const float* b_ih,
    unsigned short* e16, unsigned short* h16, float* out,
    const unsigned short* e0c, const float* ehid,
    unsigned* abortf, unsigned* s2, unsigned* s3, unsigned* s4, int tid)
{
  gbar_slow(s2, rg, sl, 1u, tid);
  unsigned a = ld_mall(abortf + rg);
  if (a == 0u) return;                       // island healthy: fast results stand

  // restore this block's slices from pristine state (sc1)
  const size_t base = (size_t)rg * 32768 + (size_t)sl * 1024;
  for (int i = tid; i < 1024; i += 512){
    int row = i >> 4, c = i & 15;
    st16<false>(e16 + base + row * 16 + c, (unsigned)e0c[base + row * 16 + c]);
    float v = ehid[((size_t)rg * 64 + row) * H_DIM + sl * 16 + c];
    st16<false>(h16 + HBUF + base + row * 16 + c, (unsigned)f2b(v));
  }
  gbar_slow(s2, rg, sl, 2u, tid);
  run_loop<false>(rg, sl, wA_e, wA_y, wB_ih, wB_hh, ghbuf, bias_big, b_ih,
                  e16, h16, out, ehid, s3, s4, nullptr, nullptr, tid);
}

// sync layout (unsigneds): [0,256) regs | [256,264) cnt | [272,280) abortf |
// [512,1024) fastB | [1024,1536) fastA | [1536,2048) s2 | [2048,2560) s3 | [2560,3072) s4
__global__ __launch_bounds__(512, 1)
void k_persist(const unsigned short* __restrict__ Wbig,
               const unsigned short* __restrict__ wih16,
               const float* __restrict__ bias_big,
               const float* __restrict__ b_ih,
               unsigned short* __restrict__ e16,
               unsigned short* __restrict__ h16,
               float* __restrict__ out,
               const unsigned short* __restrict__ e0c,
               const float* __restrict__ ehid,
               unsigned* __restrict__ sync)
{
  __shared__ short lds_s[65536];   // 128 KiB: [0,8192) wA_e | [8192,16384) wA_y | [16384,40960) wB_ih | [40960,65536) wB_hh
  __shared__ float ghbuf[3072];    // 12 KiB gh handoff (64 rows x 3 gates x 16)
  __shared__ unsigned s_xcd, s_rank, s_mode, s_ab;
  unsigned* regs   = sync;
  unsigned* cnt    = sync + 256;
  unsigned* abortf = sync + 272;
  unsigned* fastB  = sync + 512;
  unsigned* fastA  = sync + 1024;
  unsigned* s2     = sync + 1536;
  unsigned* s3     = sync + 2048;
  unsigned* s4     = sync + 2560;
  const int g = blockIdx.x, tid = threadIdx.x;

  if (tid == 0){
    unsigned x;
    asm volatile("s_getreg_b32 %0, hwreg(HW_REG_XCC_ID)" : "=s"(x));
    x &= 7u;
    unsigned r = __hip_atomic_fetch_add(&cnt[x], 1u, __ATOMIC_RELAXED, __HIP_MEMORY_SCOPE_AGENT);
    s_xcd = x; s_rank = r;
    asm volatile("global_store_dword %0, %1, off sc0 sc1" :: "v"(regs + g), "v"(1u) : "memory");
  }
  __syncthreads();
  if (tid < 64){
    const unsigned* p = regs + tid * 4;
    for (;;){
      u32x4 v;
      asm volatile("global_load_dwordx4 %0, %1, off sc0 sc1\n\ts_waitcnt vmcnt(0)" : "=v"(v) : "v"(p) : "memory");
      if (__all((int)((v[0] >= 1u) & (v[1] >= 1u) & (v[2] >= 1u) & (v[3] >= 1u)))) break;
      __builtin_amdgcn_s_sleep(2);
    }
  }
  __syncthreads();
  if (tid == 0){
    unsigned ok = 1u;
    for (int i = 0; i < 8; ++i){
      unsigned c = ld_mall(cnt + i);
      ok &= (c == 32u) ? 1u : 0u;
    }
    s_mode = ok;
  }
  __syncthreads();
  const bool fast = (s_mode != 0u);
  const int rg = fast ? (int)s_xcd  : (g >> 5);
  const int sl = fast ? (int)s_rank : (g & 31);

  short* wA_e  = lds_s;
  short* wA_y  = lds_s + 8192;
  short* wB_ih = lds_s + 16384;
  short* wB_hh = lds_s + 40960;

  // stage weights (k-major 16B granules): A-e = W_comb rows sl*16..+16; A-y = Wbig rows 2048+sl*16 (sl<4)
  for (int q = tid; q < 1024; q += 512){
    int kk = q & 63, c = q >> 6;
    bf16x8 v = *(const bf16x8*)(Wbig + (size_t)(sl * 16 + c) * H_DIM + kk * 8);
    *(bf16x8*)(wA_e + ((kk >> 2) * 64 + c * 4 + (kk & 3)) * 8) = v;
  }
  if (sl < 4){
    for (int q = tid; q < 1024; q += 512){
      int kk = q & 63, c = q >> 6;
      bf16x8 v = *(const bf16x8*)(Wbig + (size_t)(2048 + sl * 16 + c) * H_DIM + kk * 8);
      *(bf16x8*)(wA_y + ((kk >> 2) * 64 + c * 4 + (kk & 3)) * 8) = v;
    }
  }
  // B: 48 gate-cols of w_ih and of w_hh (w_hh lives at Wbig rows 512..2048)
  for (int q = tid; q < 3072; q += 512){
    int kk = q & 63, c = q >> 6;
    int phys = ((kk >> 2) * 192 + c * 4 + (kk & 3)) * 8;
    int row = ((c >> 4) << 9) + sl * 16 + (c & 15);
    *(bf16x8*)(wB_ih + phys) = *(const bf16x8*)(wih16 + (size_t)row * H_DIM + kk * 8);
    *(bf16x8*)(wB_hh + phys) = *(const bf16x8*)(Wbig + (size_t)(512 + row) * H_DIM + kk * 8);
  }
  __syncthreads();

  if (fast){
    (void)run_loop<true>(rg, sl, wA_e, wA_y, wB_ih, wB_hh, ghbuf, bias_big, b_ih,
                         e16, h16, out, ehid, fastB, fastA, abortf, &s_ab, tid);
    fast_epilogue(rg, sl, wA_e, wA_y, wB_ih, wB_hh, ghbuf, bias_big, b_ih,
                  e16, h16, out, e0c, ehid, abortf, s2, s3, s4, tid);
  } else {
    run_loop<false>(rg, sl, wA_e, wA_y, wB_ih, wB_hh, ghbuf, bias_big, b_ih,
                    e16, h16, out, ehid, s3, s4, nullptr, nullptr, tid);
  }
}

extern "C" void kernel_launch(void* const* d_in, const int* in_sizes, int n_in,
                              void* d_out, int out_size, void* d_ws, size_t ws_size,
                              hipStream_t stream)
{
  const float* enc   = (const float*)d_in[0];
  const float* ehid  = (const float*)d_in[1];
  const float* embW  = (const float*)d_in[2];
  const float* emb_b = (const float*)d_in[3];
  const float* w_ih  = (const float*)d_in[4];
  const float* w_hh  = (const float*)d_in[5];
  const float* b_ih  = (const float*)d_in[6];
  const float* b_hh  = (const float*)d_in[7];
  const float* out_W = (const float*)d_in[8];
  const float* out_b = (const float*)d_in[9];
  const float* reg_W = (const float*)d_in[10];
  const float* reg_b = (const float*)d_in[11];
  float* out = (float*)d_out;

  char* ws = (char*)d_ws;
  size_t off = 0;
  auto alloc = [&](size_t bytes)->char*{
    char* p = ws + off; off += (bytes + 255) & ~(size_t)255; return p;
  };
  unsigned short* Wbig    = (unsigned short*)alloc((size_t)2112 * 512 * 2);
  unsigned short* wih16   = (unsigned short*)alloc((size_t)1536 * 512 * 2);
  unsigned short* embW16  = (unsigned short*)alloc((size_t)512 * 256 * 2);
  unsigned short* regW16  = (unsigned short*)alloc((size_t)64 * 256 * 2);
  unsigned short* outWT16 = (unsigned short*)alloc((size_t)512 * 256 * 2);
  float*          bias_big= (float*)alloc((size_t)2112 * 4);
  unsigned short* e16     = (unsigned short*)alloc((size_t)262144 * 2);       // packed
  unsigned short* h16     = (unsigned short*)alloc((size_t)2 * HBUF * 2);     // 2 parity buffers, packed
  unsigned short* x016    = (unsigned short*)alloc((size_t)512 * 256 * 2);
  unsigned short* e0c     = (unsigned short*)alloc((size_t)262144 * 2);
  unsigned*       sync    = (unsigned*)alloc(16384);

  hipMemsetAsync(sync, 0, 16384, stream);

  // ---- precompute ----
  k_cast<<<(1536 * 512) / 256, 256, 0, stream>>>(w_ih, wih16, 1536 * 512);
  k_cast<<<(1536 * 512) / 256, 256, 0, stream>>>(w_hh, Wbig + (size_t)512 * 512, 1536 * 512);
  k_cast<<<(512 * 256) / 256, 256, 0, stream>>>(embW, embW16, 512 * 256);
  k_cast<<<(64 * 256) / 256, 256, 0, stream>>>(reg_W, regW16, 64 * 256);
  k_transpose_cast<<<512, 256, 0, stream>>>(out_W, outWT16);
  k_bias<<<9, 256, 0, stream>>>(embW, emb_b, out_b, b_hh, reg_W, reg_b, bias_big);
  k_init_h<<<(512 * 512) / 256, 256, 0, stream>>>(ehid, h16);
  k_x0<<<(512 * 256) / 256, 256, 0, stream>>>(enc, x016);

  // W_comb = emb_W @ out_W -> Wbig rows [0,512)
  k_gemm<<<dim3(8, 8), 256, 0, stream>>>(embW, 1, outWT16, nullptr, Wbig, 1, 512, 512, 256, 512);
  // W_or = reg_W @ out_W -> Wbig rows [2048,2112)
  k_gemm<<<dim3(8, 1), 256, 0, stream>>>(reg_W, 1, outWT16, nullptr, Wbig + (size_t)2048 * 512, 1, 64, 512, 256, 512);
  // e0 = relu(x0 @ emb_W^T + emb_b) -> PACKED e16
  k_gemm<<<dim3(8, 8), 256, 0, stream>>>(x016, 0, embW16, emb_b, e16, 4, 512, 512, 256, 512);
  // encoder projection
  k_gemm<<<dim3(1, 1120), 256, 0, stream>>>(enc, 1, regW16, reg_b, out, 3, 71680, 64, 256, 0);
  // pristine e0 copy for island restart
  k_dup<<<1024, 256, 0, stream>>>(e16, e0c);

  // ---- 140 GRU steps: XCD islands; binv-free sc0 transport; watchdog + slow-rerun safety net ----
  k_persist<<<dim3(NBLK), dim3(512), 0, stream>>>(Wbig, wih16, bias_big, b_ih,
                                                  e16, h16, out, e0c, ehid, sync);
}